// Round 1
// baseline (516.229 us; speedup 1.0000x reference)
//
#include <hip/hip_runtime.h>

namespace {
constexpr float kL2Reg  = 0.1f;
constexpr float kRho    = 1.0f;
constexpr float kSigma  = 2.0f * kL2Reg + kRho;   // 1.2
constexpr float kJitter = 1e-5f;
constexpr int   kIters  = 100;
constexpr int   MD = 16;     // constraint rows
constexpr int   ND = 32;     // variables
constexpr int   SPB = 16;    // samples per block (4 waves * 4 groups)
constexpr int   AS  = 132;   // A sample stride in float4 (528 floats; 528%32==16 -> 2-way max)
constexpr int   SS  = 36;    // s-buffer stride in floats (36%32==4 -> conflict-free b128 reads)
}

// A tile layout in LDS: per sample, 16 rows x 8 float4, f4 index xor-swizzled with row.
__device__ __forceinline__ float4 lds_a4(const float* As, int r, int j) {
    return *reinterpret_cast<const float4*>(&As[r * 32 + ((j ^ (r & 7)) << 2)]);
}
__device__ __forceinline__ float lds_a(const float* As, int r, int n) {
    return As[r * 32 + ((((n >> 2) ^ (r & 7)) << 2) | (n & 3))];
}

__global__ void __launch_bounds__(256)
admm_qp_kernel(const float* __restrict__ Ag, const float* __restrict__ bg,
               const float* __restrict__ cg, const float* __restrict__ lbg,
               const float* __restrict__ ubg, float* __restrict__ outg)
{
    __shared__ float A_lds[SPB * AS * 4];   // 33792 B
    __shared__ float S_lds[SPB * SS];       //  2304 B

    const int t = threadIdx.x;

    // ---- stage A for the block's 16 samples into LDS (coalesced, xor-swizzled f4)
    {
        const float4* src = reinterpret_cast<const float4*>(Ag) +
                            (size_t)blockIdx.x * (SPB * MD * ND / 4);
        float4* dst = reinterpret_cast<float4*>(A_lds);
        #pragma unroll
        for (int r = 0; r < (SPB * MD * ND / 4) / 256; ++r) {   // 8
            int idx = r * 256 + t;
            int smp = idx >> 7;          // 128 f4 per sample
            int row = (idx >> 3) & 15;
            int j   = idx & 7;
            dst[smp * AS + row * 8 + (j ^ (row & 7))] = src[idx];
        }
    }
    __syncthreads();

    const int lane = t & 63;
    const int l    = lane & 15;                     // lane within 16-lane group
    const int smp  = (t >> 6) * 4 + (lane >> 4);    // sample within block
    const size_t gs = (size_t)blockIdx.x * SPB + smp;
    const float* As = &A_lds[smp * AS * 4];
    float* Sb = &S_lds[smp * SS];

    // ---- own A row (row l) into registers
    float Ar[32];
    #pragma unroll
    for (int j = 0; j < 8; ++j) {
        float4 v = lds_a4(As, l, j);
        Ar[4*j+0] = v.x; Ar[4*j+1] = v.y; Ar[4*j+2] = v.z; Ar[4*j+3] = v.w;
    }

    // ---- M = A A^T + jitter*I (row l), augmented identity
    float Mrow[16], Vrow[16];
    #pragma unroll
    for (int k = 0; k < 16; ++k) {
        float acc = 0.f;
        #pragma unroll
        for (int j = 0; j < 8; ++j) {
            float4 v = lds_a4(As, k, j);
            acc += Ar[4*j+0]*v.x + Ar[4*j+1]*v.y + Ar[4*j+2]*v.z + Ar[4*j+3]*v.w;
        }
        Mrow[k] = acc + ((k == l) ? kJitter : 0.f);
        Vrow[k] = (k == l) ? 1.f : 0.f;
    }

    // ---- Gauss-Jordan inverse of M (SPD -> no pivoting). Lane l holds row l of [M|V].
    #pragma unroll
    for (int k = 0; k < 16; ++k) {
        float pk = __shfl(Mrow[k], k, 16);
        float ip = 1.f / pk;
        float f  = (l == k) ? 0.f : Mrow[k] * ip;
        #pragma unroll
        for (int j = k; j < 16; ++j) {
            float mj = __shfl(Mrow[j], k, 16);
            float nm = Mrow[j] - f * mj;
            Mrow[j] = (l == k) ? mj * ip : nm;
        }
        #pragma unroll
        for (int j = 0; j < 16; ++j) {
            float vj = __shfl(Vrow[j], k, 16);
            float nv = Vrow[j] - f * vj;
            Vrow[j] = (l == k) ? vj * ip : nv;
        }
    }

    // ---- w = Minv b (scalar per lane), while Vrow is live
    float bval = bg[gs * MD + l];
    float w = 0.f;
    #pragma unroll
    for (int k = 0; k < 16; ++k) w += Vrow[k] * __shfl(bval, k, 16);

    // ---- C = A^T Minv  (rows l and l+16 of the 32x16 C)
    float C0[16], C1[16];
    #pragma unroll
    for (int m = 0; m < 16; ++m) { C0[m] = 0.f; C1[m] = 0.f; }
    #pragma unroll
    for (int k = 0; k < 16; ++k) {
        float a0 = lds_a(As, k, l);
        float a1 = lds_a(As, k, l + 16);
        #pragma unroll
        for (int m = 0; m < 16; ++m) {
            float mv = __shfl(Vrow[m], k, 16);
            C0[m] += a0 * mv;
            C1[m] += a1 * mv;
        }
    }

    // ---- P = (I - C A)/sigma  (rows l, l+16 of 32x32)
    float P0[32], P1[32];
    #pragma unroll
    for (int n = 0; n < 32; ++n) { P0[n] = 0.f; P1[n] = 0.f; }
    #pragma unroll
    for (int m = 0; m < 16; ++m) {
        float c0 = C0[m], c1 = C1[m];
        #pragma unroll
        for (int j = 0; j < 8; ++j) {
            float4 v = lds_a4(As, m, j);
            P0[4*j+0] += c0*v.x; P0[4*j+1] += c0*v.y; P0[4*j+2] += c0*v.z; P0[4*j+3] += c0*v.w;
            P1[4*j+0] += c1*v.x; P1[4*j+1] += c1*v.y; P1[4*j+2] += c1*v.z; P1[4*j+3] += c1*v.w;
        }
    }
    constexpr float inv_sigma = 1.f / kSigma;
    #pragma unroll
    for (int n = 0; n < 32; ++n) {
        P0[n] = (((n == l)      ? 1.f : 0.f) - P0[n]) * inv_sigma;
        P1[n] = (((n == l + 16) ? 1.f : 0.f) - P1[n]) * inv_sigma;
    }

    // ---- q = A^T w ; d = q - P c
    float q0 = 0.f, q1 = 0.f;
    #pragma unroll
    for (int m = 0; m < 16; ++m) {
        float wm = __shfl(w, m, 16);
        q0 += lds_a(As, m, l) * wm;
        q1 += lds_a(As, m, l + 16) * wm;
    }
    float cv0 = cg[gs * ND + l];
    float cv1 = cg[gs * ND + l + 16];
    float d0 = q0, d1 = q1;
    #pragma unroll
    for (int n = 0; n < 16; ++n) {
        float ca = __shfl(cv0, n, 16);
        float cb = __shfl(cv1, n, 16);
        d0 -= P0[n] * ca + P0[n + 16] * cb;
        d1 -= P1[n] * ca + P1[n + 16] * cb;
    }

    // ---- ADMM iterations, all state in registers; s broadcast through tiny LDS slot
    float lb0 = lbg[gs * ND + l], lb1 = lbg[gs * ND + l + 16];
    float ub0 = ubg[gs * ND + l], ub1 = ubg[gs * ND + l + 16];
    float z0 = fminf(fmaxf(0.f, lb0), ub0);
    float z1 = fminf(fmaxf(0.f, lb1), ub1);
    float u0 = 0.f, u1 = 0.f;
    float x0 = 0.f, x1 = 0.f;

    for (int it = 0; it < kIters; ++it) {
        float s0 = kRho * (z0 - u0);
        float s1 = kRho * (z1 - u1);
        // slot l holds the pair (s[l], s[l+16])
        *reinterpret_cast<float2*>(&Sb[l * 2]) = make_float2(s0, s1);
        asm volatile("s_waitcnt lgkmcnt(0)" ::: "memory");  // wave-synchronous: no barrier needed
        x0 = d0; x1 = d1;
        #pragma unroll
        for (int k = 0; k < 8; ++k) {
            // (s[2k], s[2k+16], s[2k+1], s[2k+17]) -- uniform per group, bank-conflict-free
            float4 sp = *reinterpret_cast<const float4*>(&Sb[k * 4]);
            x0 += P0[2*k] * sp.x + P0[2*k+16] * sp.y + P0[2*k+1] * sp.z + P0[2*k+17] * sp.w;
            x1 += P1[2*k] * sp.x + P1[2*k+16] * sp.y + P1[2*k+1] * sp.z + P1[2*k+17] * sp.w;
        }
        float t0 = x0 + u0, t1 = x1 + u1;
        z0 = fminf(fmaxf(t0, lb0), ub0);
        z1 = fminf(fmaxf(t1, lb1), ub1);
        u0 = t0 - z0; u1 = t1 - z1;
    }

    outg[gs * ND + l]      = x0;
    outg[gs * ND + l + 16] = x1;
}

extern "C" void kernel_launch(void* const* d_in, const int* in_sizes, int n_in,
                              void* d_out, int out_size, void* d_ws, size_t ws_size,
                              hipStream_t stream) {
    const float* A  = (const float*)d_in[0];
    const float* b  = (const float*)d_in[1];
    const float* c  = (const float*)d_in[2];
    const float* lb = (const float*)d_in[3];
    const float* ub = (const float*)d_in[4];
    float* out = (float*)d_out;
    const int B = in_sizes[1] / MD;      // 32768 samples
    const int grid = B / SPB;            // 2048 blocks of 256 threads (16 samples each)
    admm_qp_kernel<<<grid, 256, 0, stream>>>(A, b, c, lb, ub, out);
}